// Round 1
// baseline (81.016 us; speedup 1.0000x reference)
//
#include <hip/hip_runtime.h>
#include <cstdint>
#include <cstddef>

// Problem constants (from reference): B=16, S=512, DEG=8, D=512, L=64
#define DDIM   512
#define NNODES 8192      // B*S
#define NEDGE  65536     // B*S*DEG
#define DEGN   8
#define GNCOLS 1536      // 3*D concatenated projections

typedef __attribute__((ext_vector_type(8))) short bf16x8;
typedef __attribute__((ext_vector_type(4))) float f32x4;

static __device__ __forceinline__ unsigned short f2bf(float f) {
    unsigned u = __float_as_uint(f);
    u += 0x7FFFu + ((u >> 16) & 1u);   // round-to-nearest-even
    return (unsigned short)(u >> 16);
}

// ---------------------------------------------------------------------------
// Kernel 1: convert x -> bf16 (xb) and compute the three per-node gate dots.
// One wave per row; lane j handles columns 8j..8j+7.
// ---------------------------------------------------------------------------
__global__ __launch_bounds__(256) void prep_kernel(
    const float* __restrict__ src,
    const float* __restrict__ vg_in, const float* __restrict__ vg_out,
    const float* __restrict__ vg_loop,
    unsigned short* __restrict__ xb,
    float* __restrict__ g_in, float* __restrict__ g_out, float* __restrict__ g_loop)
{
    int lane = threadIdx.x & 63;
    int row  = blockIdx.x * 4 + (threadIdx.x >> 6);
    int j0   = lane * 8;

    const float* x = src + (size_t)row * DDIM + j0;
    float4 x0 = *(const float4*)x;
    float4 x1 = *(const float4*)(x + 4);
    float xs[8] = {x0.x, x0.y, x0.z, x0.w, x1.x, x1.y, x1.z, x1.w};

    alignas(16) unsigned short h[8];
#pragma unroll
    for (int i = 0; i < 8; ++i) h[i] = f2bf(xs[i]);
    *(uint4*)(xb + (size_t)row * DDIM + j0) = *(const uint4*)h;

    const float* A = vg_in + j0;
    const float* Bp = vg_out + j0;
    const float* C = vg_loop + j0;
    float s0 = 0.f, s1 = 0.f, s2 = 0.f;
#pragma unroll
    for (int i = 0; i < 8; ++i) {
        s0 += xs[i] * A[i];
        s1 += xs[i] * Bp[i];
        s2 += xs[i] * C[i];
    }
#pragma unroll
    for (int o = 32; o > 0; o >>= 1) {
        s0 += __shfl_xor(s0, o);
        s1 += __shfl_xor(s1, o);
        s2 += __shfl_xor(s2, o);
    }
    if (lane == 0) {
        g_in[row] = s0; g_out[row] = s1; g_loop[row] = s2;
    }
}

// ---------------------------------------------------------------------------
// Kernel 2: weights -> bf16, transposed to N-major: wbt[n][k] = Wcat[k][n]
// n = w*512 + c for w in {in, out, loop}. Coalesced reads, small scattered
// writes (1.5 MB total, L2-absorbed).
// ---------------------------------------------------------------------------
__global__ __launch_bounds__(256) void wconv_kernel(
    const float* __restrict__ v_in, const float* __restrict__ v_out,
    const float* __restrict__ w_loop, unsigned short* __restrict__ wbt)
{
    int i = blockIdx.x * 256 + threadIdx.x;   // 0 .. 3*262144-1
    int w = i >> 18;
    int r = i & 262143;                        // k*512 + c
    const float* s = (w == 0) ? v_in : ((w == 1) ? v_out : w_loop);
    int k = r >> 9;
    int c = r & 511;
    wbt[(size_t)((w << 9) + c) * DDIM + k] = f2bf(s[r]);
}

// ---------------------------------------------------------------------------
// Kernel 3: bf16 MFMA GEMM  P[8192 x 1536] = xb[8192 x 512] @ Wcat[512 x 1536]
// 128x128 tile, BK=32, 4 waves (2x2), 16x16x32 MFMA, global_load_lds width 16.
// LDS layout [kb][row][8] (kb = k-block of 8): linear in staging lane order
// AND conflict-free for ds_read_b128 fragment loads.
// P stored as bf16.
// ---------------------------------------------------------------------------
__global__ __launch_bounds__(256) void gemm_kernel(
    const unsigned short* __restrict__ xb,
    const unsigned short* __restrict__ wbt,
    unsigned short* __restrict__ P)
{
    __shared__ short lds_a[4096];   // [4][128][8] shorts = 8 KB
    __shared__ short lds_b[4096];

    int tid  = threadIdx.x;
    int lane = tid & 63;
    int wid  = tid >> 6;
    int tm = blockIdx.x / 12, tn = blockIdx.x % 12;
    int row0 = tm * 128, col0 = tn * 128;
    int wm = wid >> 1, wn = wid & 1;

    int srow = tid & 127;     // staging row within tile
    int skb  = tid >> 7;      // staging k-block (0/1), round p adds p*2

    f32x4 acc[4][4];
#pragma unroll
    for (int m = 0; m < 4; ++m)
#pragma unroll
        for (int n = 0; n < 4; ++n) acc[m][n] = (f32x4){0.f, 0.f, 0.f, 0.f};

    const unsigned short* ga = xb  + (size_t)(row0 + srow) * DDIM + skb * 8;
    const unsigned short* gb = wbt + (size_t)(col0 + srow) * DDIM + skb * 8;

    int r16 = lane & 15, kq = lane >> 4;

    for (int kt = 0; kt < 16; ++kt) {
        int k0 = kt * 32;
        __syncthreads();   // previous tile's compute done before overwrite
#pragma unroll
        for (int p = 0; p < 2; ++p) {
            __builtin_amdgcn_global_load_lds(
                (__attribute__((address_space(1))) void*)(uintptr_t)(ga + k0 + p * 16),
                (__attribute__((address_space(3))) void*)(lds_a + p * 2048 + wid * 512),
                16, 0, 0);
            __builtin_amdgcn_global_load_lds(
                (__attribute__((address_space(1))) void*)(uintptr_t)(gb + k0 + p * 16),
                (__attribute__((address_space(3))) void*)(lds_b + p * 2048 + wid * 512),
                16, 0, 0);
        }
        __syncthreads();   // compiler drains vmcnt before barrier

        bf16x8 af[4], bfr[4];
#pragma unroll
        for (int m = 0; m < 4; ++m)
            af[m] = *(const bf16x8*)(lds_a + kq * 1024 + (wm * 64 + m * 16 + r16) * 8);
#pragma unroll
        for (int n = 0; n < 4; ++n)
            bfr[n] = *(const bf16x8*)(lds_b + kq * 1024 + (wn * 64 + n * 16 + r16) * 8);
#pragma unroll
        for (int m = 0; m < 4; ++m)
#pragma unroll
            for (int n = 0; n < 4; ++n)
                acc[m][n] = __builtin_amdgcn_mfma_f32_16x16x32_bf16(
                    af[m], bfr[n], acc[m][n], 0, 0, 0);
    }

    // Epilogue: C/D layout col = lane&15, row = (lane>>4)*4 + reg  [m89/m91]
#pragma unroll
    for (int m = 0; m < 4; ++m) {
        int grow = row0 + wm * 64 + m * 16 + kq * 4;
#pragma unroll
        for (int n = 0; n < 4; ++n) {
            int gcol = col0 + wn * 64 + n * 16 + r16;
#pragma unroll
            for (int r = 0; r < 4; ++r)
                P[(size_t)(grow + r) * GNCOLS + gcol] = f2bf(acc[m][n][r]);
        }
    }
}

// ---------------------------------------------------------------------------
// Kernel 4: per-node gather-aggregate + sigmoid gating + LayerNorm + relu +
// residual. One wave per node, lane j owns columns 8j..8j+7.
// ---------------------------------------------------------------------------
__global__ __launch_bounds__(256) void agg_kernel(
    const unsigned short* __restrict__ P,
    const float* __restrict__ g_in, const float* __restrict__ g_out,
    const float* __restrict__ g_loop,
    const int* __restrict__ arc_in, const int* __restrict__ lbl_in,
    const int* __restrict__ arc_out, const int* __restrict__ lbl_out,
    const float* __restrict__ mask_in, const float* __restrict__ mask_out,
    const float* __restrict__ mask_loop, const float* __restrict__ sent_mask,
    const float* __restrict__ b_in, const float* __restrict__ b_out,
    const float* __restrict__ bg_in, const float* __restrict__ bg_out,
    const float* __restrict__ ln_g, const float* __restrict__ ln_b,
    const float* __restrict__ src, float* __restrict__ out)
{
    int lane = threadIdx.x & 63;
    int n    = blockIdx.x * 4 + (threadIdx.x >> 6);
    int j0   = lane * 8;

    float acc[8] = {0.f, 0.f, 0.f, 0.f, 0.f, 0.f, 0.f, 0.f};

    // in-arcs (P columns 0..511)
    for (int k = 0; k < DEGN; ++k) {
        int e  = n * DEGN + k;
        int sn = arc_in[e] * 512 + arc_in[NEDGE + e];
        int lb = lbl_in[e];
        float gate = g_in[sn] + bg_in[lb];
        float s = mask_in[e] / (1.0f + __expf(-gate));
        uint4 pv = *(const uint4*)(P + (size_t)sn * GNCOLS + j0);
        const float* br = b_in + lb * DDIM + j0;
        float4 bb0 = *(const float4*)br;
        float4 bb1 = *(const float4*)(br + 4);
        const unsigned* pw = (const unsigned*)&pv;
        float pf[8];
        pf[0] = __uint_as_float(pw[0] << 16); pf[1] = __uint_as_float(pw[0] & 0xffff0000u);
        pf[2] = __uint_as_float(pw[1] << 16); pf[3] = __uint_as_float(pw[1] & 0xffff0000u);
        pf[4] = __uint_as_float(pw[2] << 16); pf[5] = __uint_as_float(pw[2] & 0xffff0000u);
        pf[6] = __uint_as_float(pw[3] << 16); pf[7] = __uint_as_float(pw[3] & 0xffff0000u);
        float bb[8] = {bb0.x, bb0.y, bb0.z, bb0.w, bb1.x, bb1.y, bb1.z, bb1.w};
#pragma unroll
        for (int i = 0; i < 8; ++i) acc[i] += s * (pf[i] + bb[i]);
    }
    // out-arcs (P columns 512..1023)
    for (int k = 0; k < DEGN; ++k) {
        int e  = n * DEGN + k;
        int sn = arc_out[e] * 512 + arc_out[NEDGE + e];
        int lb = lbl_out[e];
        float gate = g_out[sn] + bg_out[lb];
        float s = mask_out[e] / (1.0f + __expf(-gate));
        uint4 pv = *(const uint4*)(P + (size_t)sn * GNCOLS + 512 + j0);
        const float* br = b_out + lb * DDIM + j0;
        float4 bb0 = *(const float4*)br;
        float4 bb1 = *(const float4*)(br + 4);
        const unsigned* pw = (const unsigned*)&pv;
        float pf[8];
        pf[0] = __uint_as_float(pw[0] << 16); pf[1] = __uint_as_float(pw[0] & 0xffff0000u);
        pf[2] = __uint_as_float(pw[1] << 16); pf[3] = __uint_as_float(pw[1] & 0xffff0000u);
        pf[4] = __uint_as_float(pw[2] << 16); pf[5] = __uint_as_float(pw[2] & 0xffff0000u);
        pf[6] = __uint_as_float(pw[3] << 16); pf[7] = __uint_as_float(pw[3] & 0xffff0000u);
        float bb[8] = {bb0.x, bb0.y, bb0.z, bb0.w, bb1.x, bb1.y, bb1.z, bb1.w};
#pragma unroll
        for (int i = 0; i < 8; ++i) acc[i] += s * (pf[i] + bb[i]);
    }
    // self-loop (P columns 1024..1535, no label bias)
    {
        float s = mask_loop[n] / (1.0f + __expf(-g_loop[n]));
        uint4 pv = *(const uint4*)(P + (size_t)n * GNCOLS + 1024 + j0);
        const unsigned* pw = (const unsigned*)&pv;
        float pf[8];
        pf[0] = __uint_as_float(pw[0] << 16); pf[1] = __uint_as_float(pw[0] & 0xffff0000u);
        pf[2] = __uint_as_float(pw[1] << 16); pf[3] = __uint_as_float(pw[1] & 0xffff0000u);
        pf[4] = __uint_as_float(pw[2] << 16); pf[5] = __uint_as_float(pw[2] & 0xffff0000u);
        pf[6] = __uint_as_float(pw[3] << 16); pf[7] = __uint_as_float(pw[3] & 0xffff0000u);
#pragma unroll
        for (int i = 0; i < 8; ++i) acc[i] += s * pf[i];
    }

    // LayerNorm over D=512 within the wave
    float sum = 0.f, sq = 0.f;
#pragma unroll
    for (int i = 0; i < 8; ++i) { sum += acc[i]; sq += acc[i] * acc[i]; }
#pragma unroll
    for (int o = 32; o > 0; o >>= 1) {
        sum += __shfl_xor(sum, o);
        sq  += __shfl_xor(sq, o);
    }
    float mu   = sum * (1.0f / 512.0f);
    float var  = sq * (1.0f / 512.0f) - mu * mu;
    float rstd = rsqrtf(var + 1e-5f);
    float sm   = sent_mask[n];

    float4 gg0 = *(const float4*)(ln_g + j0);
    float4 gg1 = *(const float4*)(ln_g + j0 + 4);
    float4 be0 = *(const float4*)(ln_b + j0);
    float4 be1 = *(const float4*)(ln_b + j0 + 4);
    const float* sr = src + (size_t)n * DDIM + j0;
    float4 s0 = *(const float4*)sr;
    float4 s1 = *(const float4*)(sr + 4);
    float gl[8] = {gg0.x, gg0.y, gg0.z, gg0.w, gg1.x, gg1.y, gg1.z, gg1.w};
    float bt[8] = {be0.x, be0.y, be0.z, be0.w, be1.x, be1.y, be1.z, be1.w};
    float srs[8] = {s0.x, s0.y, s0.z, s0.w, s1.x, s1.y, s1.z, s1.w};

    float o_[8];
#pragma unroll
    for (int i = 0; i < 8; ++i) {
        float v = (acc[i] - mu) * rstd * gl[i] + bt[i];
        v *= sm;
        v = fmaxf(v, 0.f);
        o_[i] = v * sm + srs[i];
    }
    float4 w0 = {o_[0], o_[1], o_[2], o_[3]};
    float4 w1 = {o_[4], o_[5], o_[6], o_[7]};
    float* op = out + (size_t)n * DDIM + j0;
    *(float4*)op = w0;
    *(float4*)(op + 4) = w1;
}

// ---------------------------------------------------------------------------
// Workspace layout (bytes):
//   xb    : 0          .. 8,388,608   (8192*512 bf16)
//   wbt   : 8,388,608  .. 9,961,472   (1536*512 bf16)
//   g_in  : 9,961,472  (+32768)
//   g_out : 9,994,240  (+32768)
//   g_loop: 10,027,008 (+32768)
//   P     : 10,059,776 .. 35,225,600  (8192*1536 bf16)
// ---------------------------------------------------------------------------
extern "C" void kernel_launch(void* const* d_in, const int* in_sizes, int n_in,
                              void* d_out, int out_size, void* d_ws, size_t ws_size,
                              hipStream_t stream)
{
    const float* src       = (const float*)d_in[0];
    const int*   arc_in    = (const int*)d_in[1];
    const int*   lbl_in    = (const int*)d_in[2];
    const int*   arc_out   = (const int*)d_in[3];
    const int*   lbl_out   = (const int*)d_in[4];
    const float* mask_in   = (const float*)d_in[5];
    const float* mask_out  = (const float*)d_in[6];
    const float* mask_loop = (const float*)d_in[7];
    const float* sent_mask = (const float*)d_in[8];
    const float* V_in      = (const float*)d_in[9];
    const float* b_in      = (const float*)d_in[10];
    const float* Vg_in     = (const float*)d_in[11];
    const float* bg_in     = (const float*)d_in[12];
    const float* V_out     = (const float*)d_in[13];
    const float* b_out     = (const float*)d_in[14];
    const float* Vg_out    = (const float*)d_in[15];
    const float* bg_out    = (const float*)d_in[16];
    const float* W_loop    = (const float*)d_in[17];
    const float* Wg_loop   = (const float*)d_in[18];
    const float* ln_g      = (const float*)d_in[19];
    const float* ln_b      = (const float*)d_in[20];

    uint8_t* ws = (uint8_t*)d_ws;
    unsigned short* xb    = (unsigned short*)(ws);
    unsigned short* wbt   = (unsigned short*)(ws + 8388608);
    float*          g_in  = (float*)(ws + 9961472);
    float*          g_out = (float*)(ws + 9994240);
    float*          g_lp  = (float*)(ws + 10027008);
    unsigned short* P     = (unsigned short*)(ws + 10059776);

    prep_kernel<<<2048, 256, 0, stream>>>(src, Vg_in, Vg_out, Wg_loop, xb, g_in, g_out, g_lp);
    wconv_kernel<<<3072, 256, 0, stream>>>(V_in, V_out, W_loop, wbt);
    gemm_kernel<<<768, 256, 0, stream>>>(xb, wbt, P);
    agg_kernel<<<2048, 256, 0, stream>>>(P, g_in, g_out, g_lp,
                                         arc_in, lbl_in, arc_out, lbl_out,
                                         mask_in, mask_out, mask_loop, sent_mask,
                                         b_in, b_out, bg_in, bg_out,
                                         ln_g, ln_b, src, (float*)d_out);
}